// Round 3
// baseline (534.331 us; speedup 1.0000x reference)
//
#include <hip/hip_runtime.h>
#include <math.h>

#define NROWS 65536
#define DDIM  64
#define KCB   1024

// ---------------------------------------------------------------------------
// Kernel 1: C2[j] = ||W_j||^2 via numpy pairwise-sum emulation (n=64: 8 accs).
// Bit-exact vs np.sum(W*W, axis=1) — validated in R1 (absmax 0).
// ---------------------------------------------------------------------------
__global__ void vq_c2_kernel(const float* __restrict__ W, float* __restrict__ C2) {
    int j = blockIdx.x * blockDim.x + threadIdx.x;
    if (j >= KCB) return;
    const float* w = W + (size_t)j * DDIM;
    float r[8];
#pragma unroll
    for (int m = 0; m < 8; ++m) r[m] = __fmul_rn(w[m], w[m]);
#pragma unroll
    for (int i = 8; i < 64; i += 8) {
#pragma unroll
        for (int m = 0; m < 8; ++m)
            r[m] = __fadd_rn(r[m], __fmul_rn(w[i + m], w[i + m]));
    }
    float res = __fadd_rn(
        __fadd_rn(__fadd_rn(r[0], r[1]), __fadd_rn(r[2], r[3])),
        __fadd_rn(__fadd_rn(r[4], r[5]), __fadd_rn(r[6], r[7])));
    C2[j] = res;
}

// ---------------------------------------------------------------------------
// Kernel 2 (fused main + gather). Block = 256 threads = 4 waves, owns 64 rows.
// Lane l handles row block*64+l; wave s scans codes [s*256, s*256+256).
// W rows and C2[j] are wave-uniform -> scalar (SMEM) broadcast loads, W is
// L2-resident (256 KB/XCD). dist emulates numpy fp32 exactly:
// (L2 - 2*CL) + C2 with CL = sequential k-ascending fp32 FMA chain
// (validated absmax 0 in R1 — do not change rounding order/ops).
// First-index tie-break: strict < scan, j ascending, s-ascending combine.
// __launch_bounds__(256,2): 256-VGPR cap so xv[64] stays in real VGPRs
// (R1's (256,4) gave VGPR_Count=40 -> xv in AGPRs -> ~2x VALU issue).
// ---------------------------------------------------------------------------
__global__ void __launch_bounds__(256, 2)
vq_main_kernel(const float* __restrict__ x, const float* __restrict__ W,
               const float* __restrict__ C2, float* __restrict__ outq,
               float* __restrict__ outi) {
    __shared__ float s_bd[4][64];
    __shared__ int   s_bi[4][64];

    const int lane = threadIdx.x & 63;
    const int s    = threadIdx.x >> 6;       // wave id, uniform within wave
    const int row  = blockIdx.x * 64 + lane;

    // Load this row of x into registers (16 x float4).
    const float* xr = x + (size_t)row * DDIM;
    float xv[64];
#pragma unroll
    for (int k = 0; k < 64; k += 4) {
        float4 v = *(const float4*)(xr + k);
        xv[k] = v.x; xv[k + 1] = v.y; xv[k + 2] = v.z; xv[k + 3] = v.w;
    }

    // L2 = numpy pairwise sum of x*x (n=64).
    float r[8];
#pragma unroll
    for (int m = 0; m < 8; ++m) r[m] = __fmul_rn(xv[m], xv[m]);
#pragma unroll
    for (int i = 8; i < 64; i += 8) {
#pragma unroll
        for (int m = 0; m < 8; ++m)
            r[m] = __fadd_rn(r[m], __fmul_rn(xv[i + m], xv[i + m]));
    }
    const float L2 = __fadd_rn(
        __fadd_rn(__fadd_rn(r[0], r[1]), __fadd_rn(r[2], r[3])),
        __fadd_rn(__fadd_rn(r[4], r[5]), __fadd_rn(r[6], r[7])));

    const int j0 = s * 256;
    float best;
    int   bidx = j0;
    {   // seed with j = j0 (avoids INFINITY under possible fast-math)
        const float* wr = W + (size_t)j0 * DDIM;
        float acc = 0.0f;
#pragma unroll
        for (int k = 0; k < 64; ++k)
            acc = __builtin_fmaf(xv[k], wr[k], acc);
        best = __fadd_rn(__fsub_rn(L2, __fmul_rn(2.0f, acc)), C2[j0]);
    }
    for (int jj = 1; jj < 256; ++jj) {
        const int j = j0 + jj;
        const float* wr = W + (size_t)j * DDIM;  // wave-uniform -> s_load
        float acc = 0.0f;
#pragma unroll
        for (int k = 0; k < 64; ++k)
            acc = __builtin_fmaf(xv[k], wr[k], acc);
        const float dist = __fadd_rn(__fsub_rn(L2, __fmul_rn(2.0f, acc)), C2[j]);
        if (dist < best) { best = dist; bidx = j; }  // strict <: keep lowest j
    }

    s_bd[s][lane] = best;
    s_bi[s][lane] = bidx;
    __syncthreads();

    if (s == 0) {
        float b  = s_bd[0][lane];
        int   bi = s_bi[0][lane];
#pragma unroll
        for (int t = 1; t < 4; ++t) {
            const float d = s_bd[t][lane];
            if (d < b) { b = d; bi = s_bi[t][lane]; }  // ascending j-ranges
        }
        outi[row] = (float)bi;   // harness reads indices as fp32
        s_bi[0][lane] = bi;      // broadcast final index for the gather
    }
    __syncthreads();

    // Fused gather: 4 threads per row, 16 floats (4 x float4) each.
    {
        const int t      = threadIdx.x;
        const int rloc   = t >> 2;            // 0..63
        const int quart  = t & 3;             // 0..3
        const int j      = s_bi[0][rloc];
        const float* src = W + (size_t)j * DDIM + quart * 16;
        float* dst = outq + ((size_t)blockIdx.x * 64 + rloc) * DDIM + quart * 16;
#pragma unroll
        for (int u = 0; u < 4; ++u)
            *(float4*)(dst + 4 * u) = *(const float4*)(src + 4 * u);
    }
}

extern "C" void kernel_launch(void* const* d_in, const int* in_sizes, int n_in,
                              void* d_out, int out_size, void* d_ws, size_t ws_size,
                              hipStream_t stream) {
    const float* x = (const float*)d_in[0];
    const float* W = (const float*)d_in[1];

    float* outq = (float*)d_out;                        // N*D quantized
    float* outi = (float*)d_out + (size_t)NROWS * DDIM; // N indices as float

    float* C2 = (float*)d_ws;                           // 4 KB scratch

    hipLaunchKernelGGL(vq_c2_kernel, dim3(KCB / 256), dim3(256), 0, stream, W, C2);
    hipLaunchKernelGGL(vq_main_kernel, dim3(NROWS / 64), dim3(256), 0, stream,
                       x, W, C2, outq, outi);
}

// Round 4
// 272.924 us; speedup vs baseline: 1.9578x; 1.9578x over previous
//
#include <hip/hip_runtime.h>
#include <math.h>

#define NROWS 65536
#define DDIM  64
#define KCB   1024

// ---------------------------------------------------------------------------
// Single fused kernel. Block = 256 threads = 4 waves, owns 64 rows.
//
// Phase 0: block recomputes C2[j] = ||W_j||^2 for all 1024 codes into LDS
//          using the exact numpy pairwise-sum pattern (validated absmax 0 in
//          R1/R3 — do not change op order). 4 codes/thread, ~0.2 us.
// Phase 1: lane l scans codes for row block*64+l; wave s covers
//          [s*256, s*256+256). s comes from readfirstlane -> j is provably
//          uniform -> W rows load via SMEM (s_load_dwordx16) into SGPRs.
//          (R3 lesson: without readfirstlane, W falls to per-lane VMEM loads,
//          SGPR 96->32, VALUBusy 74->26%, 165->498 us.)
//          TWO codes (j, j+1) are scanned with interleaved independent FMA
//          chains: alternating 2-cyc issues space each chain at its ~4-cyc
//          dep latency -> ~100% per-wave VALU duty (R1's single chain capped
//          at 50%). Each chain's FP order is unchanged -> bit-exact.
//          dist = (L2 - 2*CL) + C2 in numpy order; strict < ascending j.
// Phase 2: s-ascending LDS combine (first-index tie-break), index written as
//          float to d_out tail; fused coalesced gather of W[closest].
// ---------------------------------------------------------------------------
__global__ void __launch_bounds__(256, 2)
vq_fused_kernel(const float* __restrict__ x, const float* __restrict__ W,
                float* __restrict__ outq, float* __restrict__ outi) {
    __shared__ float c2s[KCB];      // 4 KB
    __shared__ float s_bd[4][64];
    __shared__ int   s_bi[4][64];

    const int lane = threadIdx.x & 63;
    const int s    = __builtin_amdgcn_readfirstlane(threadIdx.x >> 6);
    const int row  = blockIdx.x * 64 + lane;

    // ---- load this row of x into registers (16 x float4) ----
    const float* xr = x + (size_t)row * DDIM;
    float xv[64];
#pragma unroll
    for (int k = 0; k < 64; k += 4) {
        float4 v = *(const float4*)(xr + k);
        xv[k] = v.x; xv[k + 1] = v.y; xv[k + 2] = v.z; xv[k + 3] = v.w;
    }

    // ---- Phase 0: C2 into LDS, exact numpy pairwise sum (n=64: 8 accs) ----
    {
        const int jbase = threadIdx.x * 4;   // 256 threads * 4 codes = 1024
#pragma unroll
        for (int c = 0; c < 4; ++c) {
            const float* w = W + (size_t)(jbase + c) * DDIM;
            float r[8];
#pragma unroll
            for (int m = 0; m < 8; ++m) r[m] = __fmul_rn(w[m], w[m]);
#pragma unroll
            for (int i = 8; i < 64; i += 8) {
#pragma unroll
                for (int m = 0; m < 8; ++m)
                    r[m] = __fadd_rn(r[m], __fmul_rn(w[i + m], w[i + m]));
            }
            c2s[jbase + c] = __fadd_rn(
                __fadd_rn(__fadd_rn(r[0], r[1]), __fadd_rn(r[2], r[3])),
                __fadd_rn(__fadd_rn(r[4], r[5]), __fadd_rn(r[6], r[7])));
        }
    }

    // ---- L2 = numpy pairwise sum of x*x ----
    float r[8];
#pragma unroll
    for (int m = 0; m < 8; ++m) r[m] = __fmul_rn(xv[m], xv[m]);
#pragma unroll
    for (int i = 8; i < 64; i += 8) {
#pragma unroll
        for (int m = 0; m < 8; ++m)
            r[m] = __fadd_rn(r[m], __fmul_rn(xv[i + m], xv[i + m]));
    }
    const float L2 = __fadd_rn(
        __fadd_rn(__fadd_rn(r[0], r[1]), __fadd_rn(r[2], r[3])),
        __fadd_rn(__fadd_rn(r[4], r[5]), __fadd_rn(r[6], r[7])));

    __syncthreads();   // c2s ready

    // ---- Phase 1: scan 256 codes, 2 interleaved chains per iteration ----
    const int j0 = s * 256;
    float best = INFINITY;
    int   bidx = j0;
    for (int jj = 0; jj < 256; jj += 2) {
        const int j = j0 + jj;                   // uniform (s is SGPR)
        const float* w0 = W + (size_t)j * DDIM;  // -> s_load chunks
        float acc0 = 0.0f, acc1 = 0.0f;
#pragma unroll
        for (int k = 0; k < 64; ++k) {
            acc0 = __builtin_fmaf(xv[k], w0[k], acc0);
            acc1 = __builtin_fmaf(xv[k], w0[DDIM + k], acc1);
        }
        const float d0 = __fadd_rn(__fsub_rn(L2, __fmul_rn(2.0f, acc0)), c2s[j]);
        const float d1 = __fadd_rn(__fsub_rn(L2, __fmul_rn(2.0f, acc1)), c2s[j + 1]);
        if (d0 < best) { best = d0; bidx = j; }      // strict <: lowest j wins
        if (d1 < best) { best = d1; bidx = j + 1; }
    }

    s_bd[s][lane] = best;
    s_bi[s][lane] = bidx;
    __syncthreads();

    // ---- Phase 2: combine (s-ascending => first-index tie-break) ----
    if (s == 0) {
        float b  = s_bd[0][lane];
        int   bi = s_bi[0][lane];
#pragma unroll
        for (int t = 1; t < 4; ++t) {
            const float d = s_bd[t][lane];
            if (d < b) { b = d; bi = s_bi[t][lane]; }
        }
        outi[row] = (float)bi;   // harness reads indices as fp32
        s_bi[0][lane] = bi;      // broadcast for gather
    }
    __syncthreads();

    // ---- fused gather: 4 threads per row, 16 floats (4 x float4) each ----
    {
        const int t     = threadIdx.x;
        const int rloc  = t >> 2;             // 0..63
        const int quart = t & 3;              // 0..3
        const int j     = s_bi[0][rloc];
        const float* src = W + (size_t)j * DDIM + quart * 16;
        float* dst = outq + ((size_t)blockIdx.x * 64 + rloc) * DDIM + quart * 16;
#pragma unroll
        for (int u = 0; u < 4; ++u)
            *(float4*)(dst + 4 * u) = *(const float4*)(src + 4 * u);
    }
}

extern "C" void kernel_launch(void* const* d_in, const int* in_sizes, int n_in,
                              void* d_out, int out_size, void* d_ws, size_t ws_size,
                              hipStream_t stream) {
    const float* x = (const float*)d_in[0];
    const float* W = (const float*)d_in[1];

    float* outq = (float*)d_out;                        // N*D quantized
    float* outi = (float*)d_out + (size_t)NROWS * DDIM; // N indices as float

    hipLaunchKernelGGL(vq_fused_kernel, dim3(NROWS / 64), dim3(256), 0, stream,
                       x, W, outq, outi);
}

// Round 5
// 264.672 us; speedup vs baseline: 2.0188x; 1.0312x over previous
//
#include <hip/hip_runtime.h>
#include <math.h>

#define NROWS 65536
#define DDIM  64
#define KCB   1024
#define CHUNK 64                 // codes staged in LDS per step
#define NCHUNK (KCB / CHUNK)     // 16
#define CHUNK_FLOATS (CHUNK * DDIM)  // 4096 floats = 16 KB

// ---------------------------------------------------------------------------
// Single fused kernel. Block = 256 threads = 4 waves, owns 64 rows
// (lane l of every wave handles row block*64+l).
//
// R4 lesson: VALUBusy is a gfx94x formula (SIMD-16) -> reported busy is ~2x
// real on gfx950. Real issue was already ~60 us (= fp32 floor); R1/R4 were
// SMEM-L2 latency-bound (102-SGPR budget can't double-buffer 256 B W rows).
// Fix: stream W through LDS with register prefetch; consume via wave-uniform
// ds_read_b128 broadcasts (conflict-free). Codes are chunked: chunk c holds
// codes [c*64, c*64+64); wave s consumes its slice [s*16, s*16+16) of each
// chunk as 8 pairs with 2 interleaved FMA chains (fills the 4-cyc dep
// latency at 2-cyc issue).
//
// Numerics (validated absmax 0 in R1/R3/R4 — DO NOT change op order):
//   C2 = numpy pairwise sum (8 accs); L2 same; CL = sequential k-ascending
//   fp32 FMA chain; dist = (L2 - 2*CL) + C2 with explicit _rn ops.
// Tie-break: within a thread j is scanned ascending (c outer, pair inner) so
// strict < keeps the first index. Across waves the j-ranges interleave, so
// the combine is lexicographic (dist, j) — exact, since equal np-rounded
// distances are bit-identical floats here.
// ---------------------------------------------------------------------------
__global__ void __launch_bounds__(256, 4)
vq_fused_kernel(const float* __restrict__ x, const float* __restrict__ W,
                float* __restrict__ outq, float* __restrict__ outi) {
    __shared__ float wchunk[CHUNK_FLOATS];   // 16 KB staged W chunk
    __shared__ float c2s[KCB];               // 4 KB
    __shared__ float s_bd[4][64];
    __shared__ int   s_bi[4][64];

    const int tid  = threadIdx.x;
    const int lane = tid & 63;
    const int s    = __builtin_amdgcn_readfirstlane(tid >> 6);
    const int row  = blockIdx.x * 64 + lane;

    // ---- load this row of x into registers (16 x float4) ----
    const float* xr = x + (size_t)row * DDIM;
    float xv[64];
#pragma unroll
    for (int k = 0; k < 64; k += 4) {
        float4 v = *(const float4*)(xr + k);
        xv[k] = v.x; xv[k + 1] = v.y; xv[k + 2] = v.z; xv[k + 3] = v.w;
    }

    // ---- Phase 0: C2 into LDS, exact numpy pairwise sum (n=64: 8 accs) ----
    {
        const int jbase = tid * 4;           // 256 threads * 4 codes = 1024
#pragma unroll
        for (int c = 0; c < 4; ++c) {
            const float* w = W + (size_t)(jbase + c) * DDIM;
            float r[8];
#pragma unroll
            for (int m = 0; m < 8; ++m) r[m] = __fmul_rn(w[m], w[m]);
#pragma unroll
            for (int i = 8; i < 64; i += 8) {
#pragma unroll
                for (int m = 0; m < 8; ++m)
                    r[m] = __fadd_rn(r[m], __fmul_rn(w[i + m], w[i + m]));
            }
            c2s[jbase + c] = __fadd_rn(
                __fadd_rn(__fadd_rn(r[0], r[1]), __fadd_rn(r[2], r[3])),
                __fadd_rn(__fadd_rn(r[4], r[5]), __fadd_rn(r[6], r[7])));
        }
    }

    // ---- L2 = numpy pairwise sum of x*x ----
    float r[8];
#pragma unroll
    for (int m = 0; m < 8; ++m) r[m] = __fmul_rn(xv[m], xv[m]);
#pragma unroll
    for (int i = 8; i < 64; i += 8) {
#pragma unroll
        for (int m = 0; m < 8; ++m)
            r[m] = __fadd_rn(r[m], __fmul_rn(xv[i + m], xv[i + m]));
    }
    const float L2 = __fadd_rn(
        __fadd_rn(__fadd_rn(r[0], r[1]), __fadd_rn(r[2], r[3])),
        __fadd_rn(__fadd_rn(r[4], r[5]), __fadd_rn(r[6], r[7])));

    // ---- main loop: stream W chunks through LDS with register prefetch ----
    // Each thread copies 64 B x 4 of the 16 KB chunk: float4 at
    // float-offset tid*4 + n*1024 (coalesced global, contiguous ds_write).
    float best = INFINITY;
    int   bidx = 0;

    float4 pf[4];
#pragma unroll
    for (int n = 0; n < 4; ++n)
        pf[n] = *(const float4*)(W + (size_t)n * 1024 + tid * 4);

    for (int c = 0; c < NCHUNK; ++c) {
        __syncthreads();   // previous chunk fully consumed (no-op at c=0)
#pragma unroll
        for (int n = 0; n < 4; ++n)
            *(float4*)(&wchunk[n * 1024 + tid * 4]) = pf[n];
        if (c < NCHUNK - 1) {
#pragma unroll
            for (int n = 0; n < 4; ++n)
                pf[n] = *(const float4*)(W + (size_t)(c + 1) * CHUNK_FLOATS
                                           + (size_t)n * 1024 + tid * 4);
        }
        __syncthreads();   // chunk staged (also covers Phase-0 c2s at c=0)

        // wave s consumes codes [c*64 + s*16, +16) as 8 interleaved pairs
        const int jg0 = c * CHUNK + s * 16;
        const float* wl = &wchunk[s * 16 * DDIM];
        for (int p = 0; p < 8; ++p) {
            const float* w0 = wl + (size_t)(2 * p) * DDIM;  // wave-uniform
            float acc0 = 0.0f, acc1 = 0.0f;
#pragma unroll
            for (int k = 0; k < 64; ++k) {
                acc0 = __builtin_fmaf(xv[k], w0[k], acc0);
                acc1 = __builtin_fmaf(xv[k], w0[DDIM + k], acc1);
            }
            const int j = jg0 + 2 * p;
            const float d0 = __fadd_rn(__fsub_rn(L2, __fmul_rn(2.0f, acc0)), c2s[j]);
            const float d1 = __fadd_rn(__fsub_rn(L2, __fmul_rn(2.0f, acc1)), c2s[j + 1]);
            if (d0 < best) { best = d0; bidx = j; }      // ascending j in-thread
            if (d1 < best) { best = d1; bidx = j + 1; }
        }
    }

    s_bd[s][lane] = best;
    s_bi[s][lane] = bidx;
    __syncthreads();

    // ---- combine: lexicographic (dist, j) — exact first-index semantics ----
    if (s == 0) {
        float b  = s_bd[0][lane];
        int   bi = s_bi[0][lane];
#pragma unroll
        for (int t = 1; t < 4; ++t) {
            const float d = s_bd[t][lane];
            const int   i = s_bi[t][lane];
            if (d < b || (d == b && i < bi)) { b = d; bi = i; }
        }
        outi[row] = (float)bi;   // harness reads indices as fp32
        s_bi[0][lane] = bi;      // broadcast for gather
    }
    __syncthreads();

    // ---- fused gather: 4 threads per row, 16 floats (4 x float4) each ----
    {
        const int rloc  = tid >> 2;           // 0..63
        const int quart = tid & 3;            // 0..3
        const int j     = s_bi[0][rloc];
        const float* src = W + (size_t)j * DDIM + quart * 16;
        float* dst = outq + ((size_t)blockIdx.x * 64 + rloc) * DDIM + quart * 16;
#pragma unroll
        for (int u = 0; u < 4; ++u)
            *(float4*)(dst + 4 * u) = *(const float4*)(src + 4 * u);
    }
}

extern "C" void kernel_launch(void* const* d_in, const int* in_sizes, int n_in,
                              void* d_out, int out_size, void* d_ws, size_t ws_size,
                              hipStream_t stream) {
    const float* x = (const float*)d_in[0];
    const float* W = (const float*)d_in[1];

    float* outq = (float*)d_out;                        // N*D quantized
    float* outi = (float*)d_out + (size_t)NROWS * DDIM; // N indices as float

    hipLaunchKernelGGL(vq_fused_kernel, dim3(NROWS / 64), dim3(256), 0, stream,
                       x, W, outq, outi);
}